// Round 3
// baseline (401.364 us; speedup 1.0000x reference)
//
#include <hip/hip_runtime.h>
#include <hip/hip_cooperative_groups.h>

namespace cg = cooperative_groups;

// MRR on MI355X — single cooperative dispatch.
// argsort(index) of a permutation is its inverse: element j is pos slot
// index[j] if index[j] < 8192, else neg of row (index[j]-8192)/4000.
//
// Phase A: zero packed counters + scatter the 8192 pos values (131 MB read)
// Phase B: stream idx+pv, LDS pos stage + LDS u32 counters, flush as
//          2048 packed-u64 global atomics per block (262 MB read)
// Phase C: block 0 computes sample_mrr + mean from the 16 KB counter array.
//
// R1/R2 evidence: ~75 us fixed cost per dispatch in the timed region (a
// 14.5 KB fill took as long as a 512 MB fill); both rounds ~= 4 x 75 us.
// Fusing to ONE dispatch is the play. Traffic floor: 393 MB / 6.3 TB/s ~ 62 us.
//
// ws layout: [0,32KB) pos floats; [32KB,48KB) u64 cnt[2048] (4x16-bit rows
// per u64; per-row totals <= 4000 so 16-bit fields never carry).

constexpr int N_POS = 8192;
constexpr int N_NEG = 4000;
constexpr int BLOCKS = 512;    // 2 blocks/CU x 256 CU — coop co-residency
constexpr int THREADS = 512;
constexpr int NSLOT = N_POS / 4;

typedef int   vint4   __attribute__((ext_vector_type(4)));
typedef float vfloat4 __attribute__((ext_vector_type(4)));
typedef unsigned int u32;
typedef unsigned long long u64;

// 64 KB LDS -> 2 blocks/CU; launch_bounds(512,4): 4 waves/EU => 2 blocks/CU,
// VGPR cap 128 (no spill risk for this simple loop).
__global__ __launch_bounds__(THREADS, 4) void mrr_fused(
    const vint4* __restrict__ idx4, const float* __restrict__ pv,
    float* __restrict__ pos, u64* __restrict__ cnt, float* __restrict__ out,
    int nvec) {
  __shared__ float pos_lds[N_POS];   // 32 KB
  __shared__ u32   lcnt[N_POS];      // 32 KB
  __shared__ float wsum[THREADS / 64];

  cg::grid_group grid = cg::this_grid();
  const int gtid = blockIdx.x * THREADS + threadIdx.x;
  const int stride = BLOCKS * THREADS;

  // ---------- Phase A: zero cnt; scatter pos ----------
  if (gtid < NSLOT) cnt[gtid] = 0ull;
  {
    int j = gtid;
#define SC_ELEM(V, JJ)                                   \
    if ((V).x < N_POS) pos[(V).x] = pv[4 * (JJ) + 0];    \
    if ((V).y < N_POS) pos[(V).y] = pv[4 * (JJ) + 1];    \
    if ((V).z < N_POS) pos[(V).z] = pv[4 * (JJ) + 2];    \
    if ((V).w < N_POS) pos[(V).w] = pv[4 * (JJ) + 3];
    for (; j + stride < nvec; j += 2 * stride) {
      vint4 a = __builtin_nontemporal_load(&idx4[j]);
      vint4 b = __builtin_nontemporal_load(&idx4[j + stride]);
      SC_ELEM(a, j)
      SC_ELEM(b, j + stride)
    }
    for (; j < nvec; j += stride) {
      vint4 a = __builtin_nontemporal_load(&idx4[j]);
      SC_ELEM(a, j)
    }
#undef SC_ELEM
  }
  grid.sync();

  // ---------- Phase B: count ----------
  for (int i = threadIdx.x; i < N_POS; i += THREADS) {
    pos_lds[i] = pos[i];
    lcnt[i] = 0u;
  }
  __syncthreads();

  {
    const vfloat4* __restrict__ pv4 = (const vfloat4*)pv;
    int j = gtid;
#define CT_ELEM(IV, XV)                                              \
    if ((IV) >= N_POS) {                                             \
      unsigned r = (unsigned)((IV) - N_POS) / (unsigned)N_NEG;       \
      if ((XV) > pos_lds[r]) atomicAdd(&lcnt[r], 1u);                \
    }
#define CT_VEC(V, X)                                                 \
    CT_ELEM((V).x, (X).x) CT_ELEM((V).y, (X).y)                      \
    CT_ELEM((V).z, (X).z) CT_ELEM((V).w, (X).w)
    for (; j + stride < nvec; j += 2 * stride) {
      vint4 va = __builtin_nontemporal_load(&idx4[j]);
      vint4 vb = __builtin_nontemporal_load(&idx4[j + stride]);
      vfloat4 xa = __builtin_nontemporal_load(&pv4[j]);
      vfloat4 xb = __builtin_nontemporal_load(&pv4[j + stride]);
      CT_VEC(va, xa)
      CT_VEC(vb, xb)
    }
    for (; j < nvec; j += stride) {
      vint4 va = __builtin_nontemporal_load(&idx4[j]);
      vfloat4 xa = __builtin_nontemporal_load(&pv4[j]);
      CT_VEC(va, xa)
    }
#undef CT_VEC
#undef CT_ELEM
  }
  __syncthreads();

  // Flush LDS counters -> packed u64 global atomics (4 per thread).
  for (int s = threadIdx.x; s < NSLOT; s += THREADS) {
    u32 c0 = lcnt[4 * s + 0], c1 = lcnt[4 * s + 1];
    u32 c2 = lcnt[4 * s + 2], c3 = lcnt[4 * s + 3];
    u64 p = (u64)c0 | ((u64)c1 << 16) | ((u64)c2 << 32) | ((u64)c3 << 48);
    if (p) atomicAdd(&cnt[s], p);
  }
  grid.sync();

  // ---------- Phase C: finalize (block 0 only) ----------
  if (blockIdx.x == 0) {
    float lsum = 0.f;
    for (int s = threadIdx.x; s < NSLOT; s += THREADS) {
      u64 p = __hip_atomic_load(&cnt[s], __ATOMIC_RELAXED,
                                __HIP_MEMORY_SCOPE_AGENT);
#pragma unroll
      for (int e = 0; e < 4; ++e) {
        u32 c = (u32)(p >> (16 * e)) & 0xFFFFu;
        float m = 1.0f / (float)(1u + c);
        out[1 + 4 * s + e] = m;
        lsum += m;
      }
    }
#pragma unroll
    for (int off = 32; off > 0; off >>= 1) lsum += __shfl_down(lsum, off, 64);
    if ((threadIdx.x & 63) == 0) wsum[threadIdx.x >> 6] = lsum;
    __syncthreads();
    if (threadIdx.x == 0) {
      float tot = 0.f;
#pragma unroll
      for (int w = 0; w < THREADS / 64; ++w) tot += wsum[w];
      out[0] = tot / (float)N_POS;
    }
  }
}

extern "C" void kernel_launch(void* const* d_in, const int* in_sizes, int n_in,
                              void* d_out, int out_size, void* d_ws, size_t ws_size,
                              hipStream_t stream) {
  const vint4* idx4 = (const vint4*)d_in[1];
  const float* pv = (const float*)d_in[0];
  float* out = (float*)d_out;
  float* pos = (float*)d_ws;
  u64* cnt = (u64*)((char*)d_ws + 32 * 1024);
  int nvec = in_sizes[0] / 4;   // 8,194,048

  void* args[] = {(void*)&idx4, (void*)&pv, (void*)&pos,
                  (void*)&cnt,  (void*)&out, (void*)&nvec};
  hipLaunchCooperativeKernel((void*)mrr_fused, dim3(BLOCKS), dim3(THREADS),
                             args, 0, stream);
}

// Round 4
// 289.095 us; speedup vs baseline: 1.3883x; 1.3883x over previous
//
#include <hip/hip_runtime.h>

// MRR on MI355X. N_TOT = 8192 + 8192*4000 = 32,776,192 (divisible by 4).
// argsort(index) of a permutation is its inverse: element j is pos slot
// index[j] if index[j] < 8192, else neg of row (index[j]-8192)/4000.
//
// R3 lesson: ~226 us of dur_us is fixed harness restore/poison overhead
// (R3 total 401 - coop kernel 175). R1's 3-dispatch structure's kernels
// took ~63 us total — near the ~50 us traffic floor. Coop fusion regressed
// (16 waves/CU vs 32: LDS-gather latency unhidden). So: R1 structure, with
// the memset folded into scatter, full-occupancy count, unpacked counters.
//
// ws layout: [0,32KB) pos floats; [32KB,48KB) u64 cnt[2048] (4x16-bit rows
// per u64; per-row totals <= 4000 so fields never carry).

constexpr int N_POS = 8192;
constexpr int N_NEG = 4000;
constexpr int NSLOT = N_POS / 4;

typedef int   vint4   __attribute__((ext_vector_type(4)));
typedef float vfloat4 __attribute__((ext_vector_type(4)));
typedef unsigned int u32;
typedef unsigned long long u64;

// Pass 1: zero cnt + scatter the 8192 pos values. idx read #1 (131 MB),
// plain loads so idx lines land in L2/L3 for pass 2's re-read.
__global__ __launch_bounds__(256) void scatter_pos_kernel(
    const vint4* __restrict__ idx4, const float* __restrict__ pv,
    float* __restrict__ pos, u64* __restrict__ cnt, int nvec) {
  const int gtid = blockIdx.x * 256 + threadIdx.x;
  if (gtid < NSLOT) cnt[gtid] = 0ull;
  const int stride = gridDim.x * 256;
  int j = gtid;
#define SC_ELEM(V, JJ)                                   \
  if ((V).x < N_POS) pos[(V).x] = pv[4 * (JJ) + 0];      \
  if ((V).y < N_POS) pos[(V).y] = pv[4 * (JJ) + 1];      \
  if ((V).z < N_POS) pos[(V).z] = pv[4 * (JJ) + 2];      \
  if ((V).w < N_POS) pos[(V).w] = pv[4 * (JJ) + 3];
  for (; j + stride < nvec; j += 2 * stride) {
    vint4 a = idx4[j];
    vint4 b = idx4[j + stride];
    SC_ELEM(a, j)
    SC_ELEM(b, j + stride)
  }
  for (; j < nvec; j += stride) {
    vint4 a = idx4[j];
    SC_ELEM(a, j)
  }
#undef SC_ELEM
}

// Pass 2: stream idx (#2, hopefully L3-resident) + pv (NT, single use).
// LDS pos stage + unpacked u32 LDS counters; flush as packed u64 global
// atomics (1M total, 8 MB — measured cheap in R1/R3).
__global__ __launch_bounds__(1024) void count_kernel(
    const vint4* __restrict__ idx4, const vfloat4* __restrict__ pv4,
    const float* __restrict__ pos, u64* __restrict__ cnt, int nvec) {
  __shared__ float pos_lds[N_POS];   // 32 KB
  __shared__ u32   lcnt[N_POS];      // 32 KB -> 64 KB total, 2 blocks/CU,
                                     // 1024 thr => 32 waves/CU (full occ)
  for (int i = threadIdx.x; i < N_POS; i += 1024) {
    pos_lds[i] = pos[i];
    lcnt[i] = 0u;
  }
  __syncthreads();

  const int stride = gridDim.x * 1024;
  int j = blockIdx.x * 1024 + threadIdx.x;
#define CT_ELEM(IV, XV)                                              \
  if ((IV) >= N_POS) {                                               \
    unsigned r = (unsigned)((IV) - N_POS) / (unsigned)N_NEG;         \
    if ((XV) > pos_lds[r]) atomicAdd(&lcnt[r], 1u);                  \
  }
#define CT_VEC(V, X)                                                 \
  CT_ELEM((V).x, (X).x) CT_ELEM((V).y, (X).y)                        \
  CT_ELEM((V).z, (X).z) CT_ELEM((V).w, (X).w)
  for (; j + stride < nvec; j += 2 * stride) {
    vint4 va = idx4[j];
    vint4 vb = idx4[j + stride];
    vfloat4 xa = __builtin_nontemporal_load(&pv4[j]);
    vfloat4 xb = __builtin_nontemporal_load(&pv4[j + stride]);
    CT_VEC(va, xa)
    CT_VEC(vb, xb)
  }
  for (; j < nvec; j += stride) {
    vint4 va = idx4[j];
    vfloat4 xa = __builtin_nontemporal_load(&pv4[j]);
    CT_VEC(va, xa)
  }
#undef CT_VEC
#undef CT_ELEM
  __syncthreads();

  for (int s = threadIdx.x; s < NSLOT; s += 1024) {
    u32 c0 = lcnt[4 * s + 0], c1 = lcnt[4 * s + 1];
    u32 c2 = lcnt[4 * s + 2], c3 = lcnt[4 * s + 3];
    u64 p = (u64)c0 | ((u64)c1 << 16) | ((u64)c2 << 32) | ((u64)c3 << 48);
    if (p) atomicAdd(&cnt[s], p);
  }
}

// Pass 3: one block, sample_mrr + mean.
__global__ __launch_bounds__(1024) void finalize_kernel(
    const u64* __restrict__ cnt, float* __restrict__ out) {
  __shared__ float wsum[16];
  int t = threadIdx.x;
  float lsum = 0.f;
  for (int s = t; s < NSLOT; s += 1024) {
    u64 p = cnt[s];
    float m0 = 1.0f / (float)(1u + (u32)(p & 0xFFFFu));
    float m1 = 1.0f / (float)(1u + (u32)((p >> 16) & 0xFFFFu));
    float m2 = 1.0f / (float)(1u + (u32)((p >> 32) & 0xFFFFu));
    float m3 = 1.0f / (float)(1u + (u32)((p >> 48) & 0xFFFFu));
    vfloat4 m = {m0, m1, m2, m3};
    *(vfloat4*)&out[1 + 4 * s] = m;
    lsum += m0 + m1 + m2 + m3;
  }
#pragma unroll
  for (int off = 32; off > 0; off >>= 1) lsum += __shfl_down(lsum, off, 64);
  if ((t & 63) == 0) wsum[t >> 6] = lsum;
  __syncthreads();
  if (t == 0) {
    float tot = 0.f;
#pragma unroll
    for (int w = 0; w < 16; ++w) tot += wsum[w];
    out[0] = tot / (float)N_POS;
  }
}

extern "C" void kernel_launch(void* const* d_in, const int* in_sizes, int n_in,
                              void* d_out, int out_size, void* d_ws, size_t ws_size,
                              hipStream_t stream) {
  const float* pv = (const float*)d_in[0];
  const int* idx = (const int*)d_in[1];
  float* out = (float*)d_out;
  float* pos = (float*)d_ws;
  u64* cnt = (u64*)((char*)d_ws + 32 * 1024);
  int nvec = in_sizes[0] / 4;   // 8,194,048

  scatter_pos_kernel<<<2048, 256, 0, stream>>>((const vint4*)idx, pv, pos,
                                               cnt, nvec);
  count_kernel<<<512, 1024, 0, stream>>>((const vint4*)idx, (const vfloat4*)pv,
                                         pos, cnt, nvec);
  finalize_kernel<<<1, 1024, 0, stream>>>(cnt, out);
}